// Round 6
// baseline (204.190 us; speedup 1.0000x reference)
//
#include <hip/hip_runtime.h>

// CompositionalKoopmanOperators: B=32,N=64,ATTR=4,STATE=8,REL=4,GDIM=32,NF=128,pstep=2
// Round 6: exploit loop-invariance of W_e@rel_encode (rel_encode never changes
// across psteps): compute E = W_e@relE ONCE inside k_edge_fused (relE never
// leaves LDS), fuse step-0 LN/agg there; step-1 becomes a pure memory-bound
// elementwise+LN+agg pass over E (k_prop_edge2, full occupancy).

#define ROWS 2048   // B*N
typedef unsigned short u16;
typedef unsigned int u32;
typedef __attribute__((ext_vector_type(8))) short bf16x8;   // 8 bf16 = 4 VGPR
typedef __attribute__((ext_vector_type(4))) short bf16x4;
typedef __attribute__((ext_vector_type(4))) float f32x4;

__device__ __forceinline__ float bsu(u16 u) { return __uint_as_float(((u32)u) << 16); }
__device__ __forceinline__ u16 f2b(float f) {
    u32 u = __float_as_uint(f);
    u32 r = (u + 0x7fffu + ((u >> 16) & 1u)) >> 16;   // RNE
    return (u16)r;
}

// ---------------- k_prep: one-shot bf16 weight conversions (all flat) ----------------
// re_w1b 16384 | web 16384 (rp_w[:,0:128]) | oe_w1b 16384 | wrecvb 16384 |
// wsendb 16384 | pp_wb 32768 | pr_w0b 16384 | pr_w1b 4096   => 135168 total
__global__ __launch_bounds__(256)
void k_prep(const float* __restrict__ re_w1, const float* __restrict__ rp_w,
            const float* __restrict__ oe_w1, const float* __restrict__ pp_w,
            const float* __restrict__ pr_w0, const float* __restrict__ pr_w1,
            u16* __restrict__ re_w1b, u16* __restrict__ web,
            u16* __restrict__ oe_w1b, u16* __restrict__ wrecvb, u16* __restrict__ wsendb,
            u16* __restrict__ pp_wb, u16* __restrict__ pr_w0b, u16* __restrict__ pr_w1b)
{
    int idx = blockIdx.x * 256 + threadIdx.x;
    if (idx < 16384) { re_w1b[idx] = f2b(re_w1[idx]); return; }
    idx -= 16384;
    if (idx < 16384) { int r = idx >> 7, c = idx & 127;
        web[idx] = f2b(rp_w[r * 384 + c]); return; }
    idx -= 16384;
    if (idx < 16384) { oe_w1b[idx] = f2b(oe_w1[idx]); return; }
    idx -= 16384;
    if (idx < 16384) { int r = idx >> 7, c = idx & 127;
        wrecvb[idx] = f2b(rp_w[r * 384 + 128 + c]); return; }
    idx -= 16384;
    if (idx < 16384) { int r = idx >> 7, c = idx & 127;
        wsendb[idx] = f2b(rp_w[r * 384 + 256 + c]); return; }
    idx -= 16384;
    if (idx < 32768) { pp_wb[idx] = f2b(pp_w[idx]); return; }
    idx -= 32768;
    if (idx < 16384) { pr_w0b[idx] = f2b(pr_w0[idx]); return; }
    idx -= 16384;
    if (idx < 4096)  { pr_w1b[idx] = f2b(pr_w1[idx]); }
}

// ---------------- k_node: 16 rows/block; L0 VALU + 3 MFMA GEMMs (unchanged) ----------
__global__ __launch_bounds__(256)
void k_node(const float* __restrict__ attrs, const float* __restrict__ states,
            const float* __restrict__ oe_w0, const float* __restrict__ oe_b0,
            const u16* __restrict__ oe_w1b, const float* __restrict__ oe_b1,
            const float* __restrict__ re_w0, const float* __restrict__ re_b0,
            const u16* __restrict__ wrecvb, const u16* __restrict__ wsendb,
            const float* __restrict__ rp_b,
            u16* __restrict__ objb, float* __restrict__ nr, float* __restrict__ ns,
            float* __restrict__ recvT, float* __restrict__ sendT)
{
    const int r0 = blockIdx.x * 16;
    const int t = threadIdx.x;
    __shared__ float xs[16][12];
    __shared__ float w0s[1536];
    __shared__ float rw0s[2560];
    __shared__ __align__(16) u16 hb[16 * 136];
    __shared__ __align__(16) u16 ob[16 * 136];

    if (t < 192) { int row = t / 12, c = t - row * 12;
        xs[row][c] = (c < 4) ? attrs[(r0 + row) * 4 + c] : states[(r0 + row) * 8 + (c - 4)]; }
    for (int i = t; i < 1536; i += 256) w0s[i] = oe_w0[i];
    for (int i = t; i < 2560; i += 256) rw0s[i] = re_w0[i];
    __syncthreads();

    for (int e = t; e < 2048; e += 256) {
        int row = e >> 7, o = e & 127;
        float h = oe_b0[o];
#pragma unroll
        for (int k = 0; k < 12; k++) h += w0s[o * 12 + k] * xs[row][k];
        hb[row * 136 + o] = f2b(fmaxf(h, 0.f));
        float s0 = 0.f, a0 = 0.f, a1 = 0.f;
#pragma unroll
        for (int k = 0; k < 8; k++) s0 += rw0s[o * 20 + 4 + k] * xs[row][4 + k];
#pragma unroll
        for (int k = 0; k < 4; k++) {
            a0 += rw0s[o * 20 + 12 + k] * xs[row][k];
            a1 += rw0s[o * 20 + 16 + k] * xs[row][k];
        }
        nr[(r0 + row) * 128 + o] = s0 + a0 + re_b0[o];
        ns[(r0 + row) * 128 + o] = a1 - s0;
    }
    __syncthreads();

    const int wave = t >> 6, lane = t & 63, tx = lane & 15, quad = lane >> 4;

    bf16x8 afr[4];
#pragma unroll
    for (int kk = 0; kk < 4; kk++) afr[kk] = *(const bf16x8*)&hb[tx * 136 + kk * 32 + quad * 8];
    f32x4 acc[2]; acc[0] = (f32x4){0.f,0.f,0.f,0.f}; acc[1] = acc[0];
#pragma unroll
    for (int ot = 0; ot < 2; ot++) {
        int o = (wave * 2 + ot) * 16 + tx;
#pragma unroll
        for (int kk = 0; kk < 4; kk++) {
            bf16x8 bfr = *(const bf16x8*)&oe_w1b[o * 128 + kk * 32 + quad * 8];
            acc[ot] = __builtin_amdgcn_mfma_f32_16x16x32_bf16(afr[kk], bfr, acc[ot], 0, 0, 0);
        }
    }
#pragma unroll
    for (int ot = 0; ot < 2; ot++) {
        int o = (wave * 2 + ot) * 16 + tx;
        float bia = oe_b1[o];
#pragma unroll
        for (int r = 0; r < 4; r++)
            ob[(quad * 4 + r) * 136 + o] = f2b(fmaxf(acc[ot][r] + bia, 0.f));
    }
    __syncthreads();
    { int m = t >> 4, c = t & 15;
      *(uint4*)&objb[(r0 + m) * 128 + c * 8] = *(const uint4*)&ob[m * 136 + c * 8]; }

#pragma unroll
    for (int kk = 0; kk < 4; kk++) afr[kk] = *(const bf16x8*)&ob[tx * 136 + kk * 32 + quad * 8];
    f32x4 ar[2], an[2];
    ar[0] = (f32x4){0.f,0.f,0.f,0.f}; ar[1] = ar[0]; an[0] = ar[0]; an[1] = ar[0];
#pragma unroll
    for (int ot = 0; ot < 2; ot++) {
        int o = (wave * 2 + ot) * 16 + tx;
#pragma unroll
        for (int kk = 0; kk < 4; kk++) {
            bf16x8 br = *(const bf16x8*)&wrecvb[o * 128 + kk * 32 + quad * 8];
            ar[ot] = __builtin_amdgcn_mfma_f32_16x16x32_bf16(afr[kk], br, ar[ot], 0, 0, 0);
            bf16x8 bs = *(const bf16x8*)&wsendb[o * 128 + kk * 32 + quad * 8];
            an[ot] = __builtin_amdgcn_mfma_f32_16x16x32_bf16(afr[kk], bs, an[ot], 0, 0, 0);
        }
    }
#pragma unroll
    for (int ot = 0; ot < 2; ot++) {
        int o = (wave * 2 + ot) * 16 + tx;
        float rb = rp_b[o];
#pragma unroll
        for (int r = 0; r < 4; r++) {
            recvT[(r0 + quad * 4 + r) * 128 + o] = ar[ot][r] + rb;
            sendT[(r0 + quad * 4 + r) * 128 + o] = an[ot][r];
        }
    }
}

// ---------------- k_edge_fused: h0 -> relE (LDS only) -> E = W_e@relE -> step-0 LN/agg ----
__global__ __launch_bounds__(256)
void k_edge_fused(const float* __restrict__ rel_attrs,
                  const float* __restrict__ re_w0, const u16* __restrict__ re_w1b,
                  const u16* __restrict__ web, const float* __restrict__ re_b1,
                  const float* __restrict__ rp_lnw, const float* __restrict__ rp_lnb,
                  const float* __restrict__ nr, const float* __restrict__ ns,
                  const float* __restrict__ recvT, const float* __restrict__ sendT,
                  u16* __restrict__ Ebuf, u16* __restrict__ aggb)
{
    const int t = threadIdx.x;
    __shared__ __align__(16) u16 wlds[128 * 144];   // re_w1, padded (36864 B)
    __shared__ __align__(16) u16 hsb[64 * 144];     // h0 / h1 tile (18432 B)
    __shared__ float nrs[128];
    __shared__ float w0a[128][4];
    __shared__ float ras[64][4];
    __shared__ float scr[16 * 132];
    __shared__ float lnws[128], lnbs[128];

    {   // stage re_w1 bf16 -> padded 144-stride LDS
        for (int i = t; i < 2048; i += 256) {
            int r = i >> 4, c8 = i & 15;
            *(uint4*)&wlds[r * 144 + c8 * 8] = *(const uint4*)&re_w1b[r * 128 + c8 * 8];
        }
    }
    if (t < 128) {
        lnws[t] = rp_lnw[t]; lnbs[t] = rp_lnb[t];
#pragma unroll
        for (int c = 0; c < 4; c++) w0a[t][c] = re_w0[t * 20 + c];
    }
    const int wave = t >> 6, lane = t & 63, tx = lane & 15, quad = lane >> 4;

    for (int g = 0; g < 4; g++) {
        const int blkg = blockIdx.x * 4 + g;    // b*64 + i
        const int b = blkg >> 6;
        __syncthreads();   // guard scr reads of prev group + nrs/ras reuse
        if (t < 128) nrs[t] = nr[blkg * 128 + t];
        else if (t < 192) {
            int j = t - 128;
#pragma unroll
            for (int c = 0; c < 4; c++) ras[j][c] = rel_attrs[(blkg * 64 + j) * 4 + c];
        }
        __syncthreads();

        // phase 1: h0[j][o]
        for (int e = t; e < 64 * 128; e += 256) {
            int j = e >> 7, o = e & 127;
            float v = nrs[o] + ns[(b * 64 + j) * 128 + o];
#pragma unroll
            for (int c = 0; c < 4; c++) v += w0a[o][c] * ras[j][c];
            hsb[j * 144 + o] = f2b(fmaxf(v, 0.f));
        }
        __syncthreads();

        // GEMM1: relE[j][o] = relu(sum_k h0[j][k] * re_w1[o][k] + b)
        bf16x8 afr[4];
#pragma unroll
        for (int kk = 0; kk < 4; kk++)
            afr[kk] = *(const bf16x8*)&hsb[(wave * 16 + tx) * 144 + kk * 32 + quad * 8];
        f32x4 acc[8];
#pragma unroll
        for (int oo = 0; oo < 8; oo++) acc[oo] = (f32x4){0.f, 0.f, 0.f, 0.f};
#pragma unroll
        for (int oo = 0; oo < 8; oo++) {
            const int o = oo * 16 + tx;
#pragma unroll
            for (int kk = 0; kk < 4; kk++) {
                bf16x8 bfr = *(const bf16x8*)&wlds[o * 144 + kk * 32 + quad * 8];
                acc[oo] = __builtin_amdgcn_mfma_f32_16x16x32_bf16(afr[kk], bfr, acc[oo], 0, 0, 0);
            }
        }
        // epilogue1 -> h1 (relE) into own wave's 16-row band (bands are wave-private)
#pragma unroll
        for (int oo = 0; oo < 8; oo++) {
            const int o = oo * 16 + tx;
            float bia = re_b1[o];
#pragma unroll
            for (int r = 0; r < 4; r++)
                hsb[(wave * 16 + quad * 4 + r) * 144 + o] = f2b(fmaxf(acc[oo][r] + bia, 0.f));
        }
        // GEMM2: E[j][o2] = sum_o relE[j][o] * W_e[o2][o]  (A from own band, B from L2)
        bf16x8 af2[4];
#pragma unroll
        for (int kk = 0; kk < 4; kk++)
            af2[kk] = *(const bf16x8*)&hsb[(wave * 16 + tx) * 144 + kk * 32 + quad * 8];
        f32x4 acc2[8];
#pragma unroll
        for (int oo = 0; oo < 8; oo++) acc2[oo] = (f32x4){0.f, 0.f, 0.f, 0.f};
#pragma unroll
        for (int oo = 0; oo < 8; oo++) {
            const int o2 = oo * 16 + tx;
#pragma unroll
            for (int kk = 0; kk < 4; kk++) {
                bf16x8 bfr = *(const bf16x8*)&web[o2 * 128 + kk * 32 + quad * 8];
                acc2[oo] = __builtin_amdgcn_mfma_f32_16x16x32_bf16(af2[kk], bfr, acc2[oo], 0, 0, 0);
            }
        }
        // store E in C-fragment order: ((tid*8+oo)*64+lane)*4, tid = blkg*4+wave
        const int tid = blkg * 4 + wave;
#pragma unroll
        for (int oo = 0; oo < 8; oo++) {
            bf16x4 v;
            v[0] = (short)f2b(acc2[oo][0]); v[1] = (short)f2b(acc2[oo][1]);
            v[2] = (short)f2b(acc2[oo][2]); v[3] = (short)f2b(acc2[oo][3]);
            *(bf16x4*)(Ebuf + ((size_t)(tid * 8 + oo) * 64 + lane) * 4) = v;
        }

        // step-0: y = E + recvT0[i] + sendT0[j]; LN; relu; agg
        const int jrow = wave * 16 + quad * 4;
#pragma unroll
        for (int oo = 0; oo < 8; oo++) {
            const int o = oo * 16 + tx;
            float rv = recvT[blkg * 128 + o];
#pragma unroll
            for (int r = 0; r < 4; r++)
                acc2[oo][r] += rv + sendT[(b * 64 + jrow + r) * 128 + o];
        }
        float s[4], q[4];
#pragma unroll
        for (int r = 0; r < 4; r++) {
            s[r] = 0.f; q[r] = 0.f;
#pragma unroll
            for (int oo = 0; oo < 8; oo++) { s[r] += acc2[oo][r]; q[r] += acc2[oo][r] * acc2[oo][r]; }
        }
#pragma unroll
        for (int m = 1; m < 16; m <<= 1) {
#pragma unroll
            for (int r = 0; r < 4; r++) {
                s[r] += __shfl_xor(s[r], m, 64);
                q[r] += __shfl_xor(q[r], m, 64);
            }
        }
        float mu[4], rs[4];
#pragma unroll
        for (int r = 0; r < 4; r++) {
            mu[r] = s[r] * (1.f / 128.f);
            float var = q[r] * (1.f / 128.f) - mu[r] * mu[r];
            rs[r] = rsqrtf(var + 1e-5f);
        }
        float pa[8];
#pragma unroll
        for (int oo = 0; oo < 8; oo++) {
            const int o = oo * 16 + tx;
            float lw = lnws[o], lb = lnbs[o];
            float p = 0.f;
#pragma unroll
            for (int r = 0; r < 4; r++) {
                float z = (acc2[oo][r] - mu[r]) * rs[r] * lw + lb;
                p += fmaxf(z, 0.f);
            }
            pa[oo] = p;
        }
        __syncthreads();
        const int grp = wave * 4 + quad;
#pragma unroll
        for (int oo = 0; oo < 8; oo++) scr[grp * 132 + oo * 16 + tx] = pa[oo];
        __syncthreads();
        if (t < 128) {
            float sum = 0.f;
#pragma unroll
            for (int gg = 0; gg < 16; gg++) sum += scr[gg * 132 + t];
            aggb[blkg * 128 + t] = f2b(sum);
        }
    }
}

// ---------------- k_prop_edge2: step-1, no GEMM (E + recv/send -> LN -> relu -> agg) ----
__global__ __launch_bounds__(256)
void k_prop_edge2(const u16* __restrict__ Ebuf,
                  const float* __restrict__ rp_lnw, const float* __restrict__ rp_lnb,
                  const float* __restrict__ recvT, const float* __restrict__ sendT,
                  u16* __restrict__ aggb)
{
    const int blk = blockIdx.x;   // b*64 + i
    const int b = blk >> 6;
    const int t = threadIdx.x;
    __shared__ float scr[16 * 132];
    __shared__ float lnws[128], lnbs[128];
    if (t < 128) { lnws[t] = rp_lnw[t]; lnbs[t] = rp_lnb[t]; }
    __syncthreads();

    const int wave = t >> 6, lane = t & 63, tx = lane & 15, quad = lane >> 4;
    const int tid = blk * 4 + wave;
    const int jrow = wave * 16 + quad * 4;

    float y[8][4];
#pragma unroll
    for (int oo = 0; oo < 8; oo++) {
        bf16x4 v = *(const bf16x4*)(Ebuf + ((size_t)(tid * 8 + oo) * 64 + lane) * 4);
        const int o = oo * 16 + tx;
        float rv = recvT[blk * 128 + o];
#pragma unroll
        for (int r = 0; r < 4; r++)
            y[oo][r] = bsu((u16)v[r]) + rv + sendT[(b * 64 + jrow + r) * 128 + o];
    }
    float s[4], q[4];
#pragma unroll
    for (int r = 0; r < 4; r++) {
        s[r] = 0.f; q[r] = 0.f;
#pragma unroll
        for (int oo = 0; oo < 8; oo++) { s[r] += y[oo][r]; q[r] += y[oo][r] * y[oo][r]; }
    }
#pragma unroll
    for (int m = 1; m < 16; m <<= 1) {
#pragma unroll
        for (int r = 0; r < 4; r++) {
            s[r] += __shfl_xor(s[r], m, 64);
            q[r] += __shfl_xor(q[r], m, 64);
        }
    }
    float mu[4], rs[4];
#pragma unroll
    for (int r = 0; r < 4; r++) {
        mu[r] = s[r] * (1.f / 128.f);
        rs[r] = rsqrtf(q[r] * (1.f / 128.f) - mu[r] * mu[r] + 1e-5f);
    }
    float pa[8];
#pragma unroll
    for (int oo = 0; oo < 8; oo++) {
        const int o = oo * 16 + tx;
        float lw = lnws[o], lb = lnbs[o];
        float p = 0.f;
#pragma unroll
        for (int r = 0; r < 4; r++) {
            float z = (y[oo][r] - mu[r]) * rs[r] * lw + lb;
            p += fmaxf(z, 0.f);
        }
        pa[oo] = p;
    }
    const int grp = wave * 4 + quad;
#pragma unroll
    for (int oo = 0; oo < 8; oo++) scr[grp * 132 + oo * 16 + tx] = pa[oo];
    __syncthreads();
    if (t < 128) {
        float sum = 0.f;
#pragma unroll
        for (int gg = 0; gg < 16; gg++) sum += scr[gg * 132 + t];
        aggb[blk * 128 + t] = f2b(sum);
    }
}

// ---------------- k_prop_node: 16 rows/block MFMA (unchanged) ----------------
__global__ __launch_bounds__(256)
void k_prop_node(const u16* __restrict__ aggb,
                 const u16* __restrict__ pp_wb, const float* __restrict__ pp_b,
                 const float* __restrict__ pp_lnw, const float* __restrict__ pp_lnb,
                 const u16* __restrict__ wrecvb, const u16* __restrict__ wsendb,
                 const float* __restrict__ rp_b,
                 u16* __restrict__ objb, float* __restrict__ recvT, float* __restrict__ sendT,
                 int compute_terms)
{
    const int r0 = blockIdx.x * 16;
    const int t = threadIdx.x;
    __shared__ __align__(16) u16 ab[16 * 264];
    __shared__ __align__(16) u16 ob[16 * 136];
    __shared__ float redS[64], redQ[64];

    for (int i = t; i < 512; i += 256) {
        int m = i >> 5, c = i & 31;
        uint4 v = (c < 16) ? *(const uint4*)&objb[(r0 + m) * 128 + (c & 15) * 8]
                           : *(const uint4*)&aggb[(r0 + m) * 128 + (c - 16) * 8];
        *(uint4*)&ab[m * 264 + c * 8] = v;
    }
    __syncthreads();

    const int wave = t >> 6, lane = t & 63, tx = lane & 15, quad = lane >> 4;
    bf16x8 afr[8];
#pragma unroll
    for (int kk = 0; kk < 8; kk++) afr[kk] = *(const bf16x8*)&ab[tx * 264 + kk * 32 + quad * 8];
    f32x4 acc[2]; acc[0] = (f32x4){0.f,0.f,0.f,0.f}; acc[1] = acc[0];
#pragma unroll
    for (int ot = 0; ot < 2; ot++) {
        int o = (wave * 2 + ot) * 16 + tx;
#pragma unroll
        for (int kk = 0; kk < 8; kk++) {
            bf16x8 bfr = *(const bf16x8*)&pp_wb[o * 256 + kk * 32 + quad * 8];
            acc[ot] = __builtin_amdgcn_mfma_f32_16x16x32_bf16(afr[kk], bfr, acc[ot], 0, 0, 0);
        }
    }
#pragma unroll
    for (int ot = 0; ot < 2; ot++) {
        float bia = pp_b[(wave * 2 + ot) * 16 + tx];
#pragma unroll
        for (int r = 0; r < 4; r++) acc[ot][r] += bia;
    }

    float s[4], q[4];
#pragma unroll
    for (int r = 0; r < 4; r++) {
        s[r] = acc[0][r] + acc[1][r];
        q[r] = acc[0][r] * acc[0][r] + acc[1][r] * acc[1][r];
    }
#pragma unroll
    for (int m = 1; m < 16; m <<= 1) {
#pragma unroll
        for (int r = 0; r < 4; r++) {
            s[r] += __shfl_xor(s[r], m, 64);
            q[r] += __shfl_xor(q[r], m, 64);
        }
    }
    if (tx == 0) {
#pragma unroll
        for (int r = 0; r < 4; r++) {
            redS[wave * 16 + quad * 4 + r] = s[r];
            redQ[wave * 16 + quad * 4 + r] = q[r];
        }
    }
    __syncthreads();
    float mu[4], rs[4];
#pragma unroll
    for (int r = 0; r < 4; r++) {
        int m = quad * 4 + r;
        float ss = redS[m] + redS[16 + m] + redS[32 + m] + redS[48 + m];
        float qq = redQ[m] + redQ[16 + m] + redQ[32 + m] + redQ[48 + m];
        mu[r] = ss * (1.f / 128.f);
        rs[r] = rsqrtf(qq * (1.f / 128.f) - mu[r] * mu[r] + 1e-5f);
    }
#pragma unroll
    for (int ot = 0; ot < 2; ot++) {
        int o = (wave * 2 + ot) * 16 + tx;
        float lw = pp_lnw[o], lb = pp_lnb[o];
#pragma unroll
        for (int r = 0; r < 4; r++) {
            float z = (acc[ot][r] - mu[r]) * rs[r] * lw + lb;
            ob[(quad * 4 + r) * 136 + o] = f2b(fmaxf(z, 0.f));
        }
    }
    __syncthreads();
    { int m = t >> 4, c = t & 15;
      *(uint4*)&objb[(r0 + m) * 128 + c * 8] = *(const uint4*)&ob[m * 136 + c * 8]; }

    if (compute_terms) {
        bf16x8 af2[4];
#pragma unroll
        for (int kk = 0; kk < 4; kk++) af2[kk] = *(const bf16x8*)&ob[tx * 136 + kk * 32 + quad * 8];
        f32x4 ar[2], an[2];
        ar[0] = (f32x4){0.f,0.f,0.f,0.f}; ar[1] = ar[0]; an[0] = ar[0]; an[1] = ar[0];
#pragma unroll
        for (int ot = 0; ot < 2; ot++) {
            int o = (wave * 2 + ot) * 16 + tx;
#pragma unroll
            for (int kk = 0; kk < 4; kk++) {
                bf16x8 br = *(const bf16x8*)&wrecvb[o * 128 + kk * 32 + quad * 8];
                ar[ot] = __builtin_amdgcn_mfma_f32_16x16x32_bf16(af2[kk], br, ar[ot], 0, 0, 0);
                bf16x8 bs = *(const bf16x8*)&wsendb[o * 128 + kk * 32 + quad * 8];
                an[ot] = __builtin_amdgcn_mfma_f32_16x16x32_bf16(af2[kk], bs, an[ot], 0, 0, 0);
            }
        }
#pragma unroll
        for (int ot = 0; ot < 2; ot++) {
            int o = (wave * 2 + ot) * 16 + tx;
            float rb = rp_b[o];
#pragma unroll
            for (int r = 0; r < 4; r++) {
                recvT[(r0 + quad * 4 + r) * 128 + o] = ar[ot][r] + rb;
                sendT[(r0 + quad * 4 + r) * 128 + o] = an[ot][r];
            }
        }
    }
}

// ---------------- k_predict: 16 rows/block MFMA (unchanged) ----------------
__global__ __launch_bounds__(256)
void k_predict(const u16* __restrict__ objb,
               const u16* __restrict__ pr_w0b, const float* __restrict__ pr_b0,
               const u16* __restrict__ pr_w1b, const float* __restrict__ pr_b1,
               float* __restrict__ out)
{
    const int r0 = blockIdx.x * 16;
    const int t = threadIdx.x;
    __shared__ __align__(16) u16 ab[16 * 136];
    __shared__ __align__(16) u16 hb2[16 * 136];
    { int m = t >> 4, c = t & 15;
      *(uint4*)&ab[m * 136 + c * 8] = *(const uint4*)&objb[(r0 + m) * 128 + c * 8]; }
    __syncthreads();

    const int wave = t >> 6, lane = t & 63, tx = lane & 15, quad = lane >> 4;
    bf16x8 afr[4];
#pragma unroll
    for (int kk = 0; kk < 4; kk++) afr[kk] = *(const bf16x8*)&ab[tx * 136 + kk * 32 + quad * 8];
    f32x4 acc[2]; acc[0] = (f32x4){0.f,0.f,0.f,0.f}; acc[1] = acc[0];
#pragma unroll
    for (int ot = 0; ot < 2; ot++) {
        int o = (wave * 2 + ot) * 16 + tx;
#pragma unroll
        for (int kk = 0; kk < 4; kk++) {
            bf16x8 bfr = *(const bf16x8*)&pr_w0b[o * 128 + kk * 32 + quad * 8];
            acc[ot] = __builtin_amdgcn_mfma_f32_16x16x32_bf16(afr[kk], bfr, acc[ot], 0, 0, 0);
        }
    }
#pragma unroll
    for (int ot = 0; ot < 2; ot++) {
        int o = (wave * 2 + ot) * 16 + tx;
        float bia = pr_b0[o];
#pragma unroll
        for (int r = 0; r < 4; r++)
            hb2[(quad * 4 + r) * 136 + o] = f2b(fmaxf(acc[ot][r] + bia, 0.f));
    }
    __syncthreads();
    if (wave < 2) {
        bf16x8 af2[4];
#pragma unroll
        for (int kk = 0; kk < 4; kk++) af2[kk] = *(const bf16x8*)&hb2[tx * 136 + kk * 32 + quad * 8];
        f32x4 a2 = (f32x4){0.f,0.f,0.f,0.f};
        int o = wave * 16 + tx;
#pragma unroll
        for (int kk = 0; kk < 4; kk++) {
            bf16x8 bfr = *(const bf16x8*)&pr_w1b[o * 128 + kk * 32 + quad * 8];
            a2 = __builtin_amdgcn_mfma_f32_16x16x32_bf16(af2[kk], bfr, a2, 0, 0, 0);
        }
        float bia = pr_b1[o];
#pragma unroll
        for (int r = 0; r < 4; r++)
            out[(r0 + quad * 4 + r) * 32 + o] = tanhf(a2[r] + bia);
    }
}

extern "C" void kernel_launch(void* const* d_in, const int* in_sizes, int n_in,
                              void* d_out, int out_size, void* d_ws, size_t ws_size,
                              hipStream_t stream)
{
    const float* attrs    = (const float*)d_in[0];
    const float* states   = (const float*)d_in[1];
    const float* rel_attrs= (const float*)d_in[3];
    const float* oe_w0 = (const float*)d_in[4];
    const float* oe_b0 = (const float*)d_in[5];
    const float* oe_w1 = (const float*)d_in[6];
    const float* oe_b1 = (const float*)d_in[7];
    const float* re_w0 = (const float*)d_in[8];
    const float* re_b0 = (const float*)d_in[9];
    const float* re_w1 = (const float*)d_in[10];
    const float* re_b1 = (const float*)d_in[11];
    const float* rp_w  = (const float*)d_in[12];
    const float* rp_b  = (const float*)d_in[13];
    const float* rp_lnw= (const float*)d_in[14];
    const float* rp_lnb= (const float*)d_in[15];
    const float* pp_w  = (const float*)d_in[16];
    const float* pp_b  = (const float*)d_in[17];
    const float* pp_lnw= (const float*)d_in[18];
    const float* pp_lnb= (const float*)d_in[19];
    const float* pr_w0 = (const float*)d_in[20];
    const float* pr_b0 = (const float*)d_in[21];
    const float* pr_w1 = (const float*)d_in[22];
    const float* pr_b1 = (const float*)d_in[23];
    // d_in[24] = pstep (always 2)

    float* ws    = (float*)d_ws;
    float* nr    = ws;
    float* ns    = nr    + ROWS * 128;
    float* recvT = ns    + ROWS * 128;
    float* sendT = recvT + ROWS * 128;
    u16* re_w1b = (u16*)(sendT + ROWS * 128);
    u16* web    = re_w1b + 16384;
    u16* oe_w1b = web    + 16384;
    u16* wrecvb = oe_w1b + 16384;
    u16* wsendb = wrecvb + 16384;
    u16* pp_wb  = wsendb + 16384;
    u16* pr_w0b = pp_wb  + 32768;
    u16* pr_w1b = pr_w0b + 16384;
    u16* objb   = pr_w1b + 4096;
    u16* aggb   = objb + ROWS * 128;
    u16* Ebuf   = aggb + ROWS * 128;   // 8192 tiles * 8 * 64 * 4 bf16 (33.5 MB)

    k_prep<<<528, 256, 0, stream>>>(re_w1, rp_w, oe_w1, pp_w, pr_w0, pr_w1,
                                    re_w1b, web, oe_w1b, wrecvb, wsendb,
                                    pp_wb, pr_w0b, pr_w1b);
    k_node<<<128, 256, 0, stream>>>(attrs, states, oe_w0, oe_b0, oe_w1b, oe_b1,
                                    re_w0, re_b0, wrecvb, wsendb, rp_b,
                                    objb, nr, ns, recvT, sendT);
    k_edge_fused<<<512, 256, 0, stream>>>(rel_attrs, re_w0, re_w1b, web, re_b1,
                                          rp_lnw, rp_lnb, nr, ns, recvT, sendT,
                                          Ebuf, aggb);
    k_prop_node<<<128, 256, 0, stream>>>(aggb, pp_wb, pp_b, pp_lnw, pp_lnb,
                                         wrecvb, wsendb, rp_b,
                                         objb, recvT, sendT, 1);
    k_prop_edge2<<<2048, 256, 0, stream>>>(Ebuf, rp_lnw, rp_lnb, recvT, sendT, aggb);
    k_prop_node<<<128, 256, 0, stream>>>(aggb, pp_wb, pp_b, pp_lnw, pp_lnb,
                                         wrecvb, wsendb, rp_b,
                                         objb, recvT, sendT, 0);
    k_predict<<<128, 256, 0, stream>>>(objb, pr_w0b, pr_b0, pr_w1b, pr_b1, (float*)d_out);
}